// Round 7
// baseline (52.581 us; speedup 1.0000x reference)
//
#include <hip/hip_runtime.h>

// Problem constants (from reference setup_inputs)
constexpr int B = 512;
constexpr int N = 1000;    // rows per batch
constexpr int D = 128;
constexpr int F = 2;
constexpr float LN_EPS = 1e-3f;

constexpr int CHUNKS = 4;                   // row-chunks per batch
constexpr int ROWS_PER_CHUNK = N / CHUNKS;  // 250

// clang-native 4-float vector (accepted by __builtin_nontemporal_load)
typedef float fx4 __attribute__((ext_vector_type(4)));

// ---------------- Kernel A: streaming column sums ----------------
// grid = B*CHUNKS = 2048 blocks x 256 threads (8 blocks/CU).
// Capacity-split cache policy: chunks 0,1 (rows 0..499 of every batch,
// 131 MB total) use plain L3-allocating loads -> deterministically fits
// the 256 MB Infinity Cache and stays resident across graph replays.
// Chunks 2,3 use nontemporal (evict-first) loads -> stream from HBM
// without displacing the resident half.
__global__ __launch_bounds__(256) void colsum_kernel(
    const float* __restrict__ H, fx4* __restrict__ ws)
{
    const int blk = blockIdx.x;
    const int b   = blk >> 2;          // batch
    const int ch  = blk & 3;           // chunk
    const int tid = threadIdx.x;
    const int c4  = tid & 31;          // which fx4 of the 128-float row
    const int rg  = tid >> 5;          // row group 0..7

    const float* __restrict__ Hb = H + (size_t)b * (N * D);
    const int nstart = ch * ROWS_PER_CHUNK;
    const int nend   = nstart + ROWS_PER_CHUNK;

    fx4 acc = (fx4)(0.f);
    if (ch < 2) {
        // L3-resident half: plain loads (allocate L2+L3)
        #pragma unroll 8
        for (int n = nstart + rg; n < nend; n += 8)
            acc += *reinterpret_cast<const fx4*>(Hb + (size_t)n * D + c4 * 4);
    } else {
        // streaming half: nontemporal (evict-first)
        #pragma unroll 8
        for (int n = nstart + rg; n < nend; n += 8)
            acc += __builtin_nontemporal_load(
                reinterpret_cast<const fx4*>(Hb + (size_t)n * D + c4 * 4));
    }

    __shared__ fx4 sp[8][32];
    sp[rg][c4] = acc;
    __syncthreads();

    if (tid < 32) {
        fx4 s = sp[0][tid];
        #pragma unroll
        for (int g = 1; g < 8; ++g) s += sp[g][tid];
        ws[(size_t)(b * CHUNKS + ch) * 32 + tid] = s;   // plain store: L2-hot for B
    }
}

// ---------------- Kernel B: gather + dense + ReLU + LayerNorm ----------------
// grid = B blocks x 256 threads. Matvec split 8-way over K (each k-slice owns
// 48 k's, fx4 W loads); LDS combine; LN on wave-0 lanes 0..31.
__global__ __launch_bounds__(256) void gather_dense_ln(
    const float* __restrict__ H, const int* __restrict__ indice,
    const float* __restrict__ ws, const float* __restrict__ W,
    const float* __restrict__ bias, const float* __restrict__ gamma,
    const float* __restrict__ beta, float* __restrict__ out)
{
    const int b   = blockIdx.x;
    const int tid = threadIdx.x;
    const float* __restrict__ Hb = H + (size_t)b * (N * D);

    __shared__ float semb[(F + 1) * D];  // [row_i0 | row_i1 | mean]
    __shared__ fx4 sx[8][32];            // per-k-slice partial outputs

    // gather the two indexed rows: 256 threads cover 2*128 elements
    {
        const int f   = tid >> 7;            // 0 or 1
        const int col = tid & 127;
        const int idx = indice[b * F + f];
        semb[f * D + col] = Hb[(size_t)idx * D + col];
    }
    // mean row from the 4 chunk partials: threads 0..127
    if (tid < 128) {
        const float* wsf = reinterpret_cast<const float*>(ws);
        const float cs = wsf[(size_t)(b * CHUNKS + 0) * D + tid]
                       + wsf[(size_t)(b * CHUNKS + 1) * D + tid]
                       + wsf[(size_t)(b * CHUNKS + 2) * D + tid]
                       + wsf[(size_t)(b * CHUNKS + 3) * D + tid];
        semb[2 * D + tid] = cs * (1.0f / (float)N);
    }
    __syncthreads();

    // matvec: slice ksl covers k in [ksl*48, ksl*48+48), 4 indep accumulators
    {
        const int ksl = tid >> 5;
        const int c4  = tid & 31;
        const fx4* __restrict__ W4 = reinterpret_cast<const fx4*>(W);
        fx4 a0 = (fx4)(0.f), a1 = (fx4)(0.f), a2 = (fx4)(0.f), a3 = (fx4)(0.f);
        const int k0 = ksl * 48;
        #pragma unroll 4
        for (int k = k0; k < k0 + 48; k += 4) {
            a0 += semb[k + 0] * W4[(size_t)(k + 0) * 32 + c4];
            a1 += semb[k + 1] * W4[(size_t)(k + 1) * 32 + c4];
            a2 += semb[k + 2] * W4[(size_t)(k + 2) * 32 + c4];
            a3 += semb[k + 3] * W4[(size_t)(k + 3) * 32 + c4];
        }
        sx[ksl][c4] = (a0 + a1) + (a2 + a3);
    }
    __syncthreads();

    // combine slices + bias + ReLU + LayerNorm (wave 0, lanes 0..31, 4 cols each)
    if (tid < 32) {
        fx4 x = reinterpret_cast<const fx4*>(bias)[tid];
        #pragma unroll
        for (int g = 0; g < 8; ++g) x += sx[g][tid];
        x.x = fmaxf(x.x, 0.f); x.y = fmaxf(x.y, 0.f);
        x.z = fmaxf(x.z, 0.f); x.w = fmaxf(x.w, 0.f);

        float s  = x.x + x.y + x.z + x.w;
        float s2 = x.x * x.x + x.y * x.y + x.z * x.z + x.w * x.w;
        #pragma unroll
        for (int off = 1; off < 32; off <<= 1) {   // lanes 0..31: partners all active
            s  += __shfl_xor(s,  off);
            s2 += __shfl_xor(s2, off);
        }
        const float mean = s  * (1.0f / (float)D);
        const float var  = s2 * (1.0f / (float)D) - mean * mean;
        const float rstd = rsqrtf(var + LN_EPS);

        const fx4 g4 = reinterpret_cast<const fx4*>(gamma)[tid];
        const fx4 b4 = reinterpret_cast<const fx4*>(beta)[tid];
        fx4 y;
        y.x = g4.x * (x.x - mean) * rstd + b4.x;
        y.y = g4.y * (x.y - mean) * rstd + b4.y;
        y.z = g4.z * (x.z - mean) * rstd + b4.z;
        y.w = g4.w * (x.w - mean) * rstd + b4.w;
        reinterpret_cast<fx4*>(out)[(size_t)b * 32 + tid] = y;
    }
}

extern "C" void kernel_launch(void* const* d_in, const int* in_sizes, int n_in,
                              void* d_out, int out_size, void* d_ws, size_t ws_size,
                              hipStream_t stream) {
    const float* H      = (const float*)d_in[0];
    const int*   indice = (const int*)  d_in[1];
    const float* W      = (const float*)d_in[2];
    const float* bias   = (const float*)d_in[3];
    const float* gamma  = (const float*)d_in[4];
    const float* beta   = (const float*)d_in[5];
    float* out = (float*)d_out;
    fx4*   ws  = (fx4*)d_ws;   // needs B*CHUNKS*D floats = 1 MB

    colsum_kernel<<<dim3(B * CHUNKS), dim3(256), 0, stream>>>(H, ws);
    gather_dense_ln<<<dim3(B), dim3(256), 0, stream>>>(
        H, indice, (const float*)ws, W, bias, gamma, beta, out);
}

// Round 8
// 50.134 us; speedup vs baseline: 1.0488x; 1.0488x over previous
//
#include <hip/hip_runtime.h>

// Problem constants (from reference setup_inputs)
constexpr int B = 512;
constexpr int N = 1000;    // rows per batch
constexpr int D = 128;
constexpr int F = 2;
constexpr float LN_EPS = 1e-3f;

constexpr int CHUNKS = 4;                   // row-chunks per batch (known-good)
constexpr int ROWS_PER_CHUNK = N / CHUNKS;  // 250

// clang-native 4-float vector (accepted by __builtin_nontemporal_load)
typedef float fx4 __attribute__((ext_vector_type(4)));

// ---------------- Kernel A: streaming column sums ----------------
// grid = B*CHUNKS = 2048 blocks x 256 threads (8 blocks/CU).
// Each block sums 250 rows (125 KB contiguous) with nontemporal fx4 loads
// (zero reuse: bypass L2, don't fight over L3) into ws[(b*CHUNKS+ch)*32+c4].
// Measured: 5.46 TB/s read — at the read-streaming class ceiling for gfx950.
// Cache-policy variants (plain loads, hybrid, 50/50 capacity split) all
// regressed 2-6%: allocating loads pollute the 4MiB/XCD L2.
__global__ __launch_bounds__(256) void colsum_kernel(
    const float* __restrict__ H, fx4* __restrict__ ws)
{
    const int blk = blockIdx.x;
    const int b   = blk >> 2;          // batch
    const int ch  = blk & 3;           // chunk
    const int tid = threadIdx.x;
    const int c4  = tid & 31;          // which fx4 of the 128-float row
    const int rg  = tid >> 5;          // row group 0..7

    const float* __restrict__ Hb = H + (size_t)b * (N * D);
    const int nstart = ch * ROWS_PER_CHUNK;
    const int nend   = nstart + ROWS_PER_CHUNK;

    fx4 acc = (fx4)(0.f);
    #pragma unroll 8
    for (int n = nstart + rg; n < nend; n += 8)
        acc += __builtin_nontemporal_load(
            reinterpret_cast<const fx4*>(Hb + (size_t)n * D + c4 * 4));

    __shared__ fx4 sp[8][32];
    sp[rg][c4] = acc;
    __syncthreads();

    if (tid < 32) {
        fx4 s = sp[0][tid];
        #pragma unroll
        for (int g = 1; g < 8; ++g) s += sp[g][tid];
        ws[(size_t)(b * CHUNKS + ch) * 32 + tid] = s;   // plain store: L2-hot for B
    }
}

// ---------------- Kernel B: gather + dense + ReLU + LayerNorm ----------------
// grid = B blocks x 256 threads (~2 us, launch-latency-bound; internals are
// off the critical path — measured round-5 A/B delta 0.05 us).
__global__ __launch_bounds__(256) void gather_dense_ln(
    const float* __restrict__ H, const int* __restrict__ indice,
    const float* __restrict__ ws, const float* __restrict__ W,
    const float* __restrict__ bias, const float* __restrict__ gamma,
    const float* __restrict__ beta, float* __restrict__ out)
{
    const int b   = blockIdx.x;
    const int tid = threadIdx.x;
    const float* __restrict__ Hb = H + (size_t)b * (N * D);

    __shared__ float semb[(F + 1) * D];  // [row_i0 | row_i1 | mean]
    __shared__ fx4 sx[8][32];            // per-k-slice partial outputs

    // gather the two indexed rows: 256 threads cover 2*128 elements
    {
        const int f   = tid >> 7;            // 0 or 1
        const int col = tid & 127;
        const int idx = indice[b * F + f];
        semb[f * D + col] = Hb[(size_t)idx * D + col];
    }
    // mean row from the 4 chunk partials: threads 0..127
    if (tid < 128) {
        const float* wsf = reinterpret_cast<const float*>(ws);
        const float cs = wsf[(size_t)(b * CHUNKS + 0) * D + tid]
                       + wsf[(size_t)(b * CHUNKS + 1) * D + tid]
                       + wsf[(size_t)(b * CHUNKS + 2) * D + tid]
                       + wsf[(size_t)(b * CHUNKS + 3) * D + tid];
        semb[2 * D + tid] = cs * (1.0f / (float)N);
    }
    __syncthreads();

    // matvec: slice ksl covers k in [ksl*48, ksl*48+48), 4 indep accumulators
    {
        const int ksl = tid >> 5;
        const int c4  = tid & 31;
        const fx4* __restrict__ W4 = reinterpret_cast<const fx4*>(W);
        fx4 a0 = (fx4)(0.f), a1 = (fx4)(0.f), a2 = (fx4)(0.f), a3 = (fx4)(0.f);
        const int k0 = ksl * 48;
        #pragma unroll 4
        for (int k = k0; k < k0 + 48; k += 4) {
            a0 += semb[k + 0] * W4[(size_t)(k + 0) * 32 + c4];
            a1 += semb[k + 1] * W4[(size_t)(k + 1) * 32 + c4];
            a2 += semb[k + 2] * W4[(size_t)(k + 2) * 32 + c4];
            a3 += semb[k + 3] * W4[(size_t)(k + 3) * 32 + c4];
        }
        sx[ksl][c4] = (a0 + a1) + (a2 + a3);
    }
    __syncthreads();

    // combine slices + bias + ReLU + LayerNorm (wave 0, lanes 0..31, 4 cols each)
    if (tid < 32) {
        fx4 x = reinterpret_cast<const fx4*>(bias)[tid];
        #pragma unroll
        for (int g = 0; g < 8; ++g) x += sx[g][tid];
        x.x = fmaxf(x.x, 0.f); x.y = fmaxf(x.y, 0.f);
        x.z = fmaxf(x.z, 0.f); x.w = fmaxf(x.w, 0.f);

        float s  = x.x + x.y + x.z + x.w;
        float s2 = x.x * x.x + x.y * x.y + x.z * x.z + x.w * x.w;
        #pragma unroll
        for (int off = 1; off < 32; off <<= 1) {   // lanes 0..31: partners all active
            s  += __shfl_xor(s,  off);
            s2 += __shfl_xor(s2, off);
        }
        const float mean = s  * (1.0f / (float)D);
        const float var  = s2 * (1.0f / (float)D) - mean * mean;
        const float rstd = rsqrtf(var + LN_EPS);

        const fx4 g4 = reinterpret_cast<const fx4*>(gamma)[tid];
        const fx4 b4 = reinterpret_cast<const fx4*>(beta)[tid];
        fx4 y;
        y.x = g4.x * (x.x - mean) * rstd + b4.x;
        y.y = g4.y * (x.y - mean) * rstd + b4.y;
        y.z = g4.z * (x.z - mean) * rstd + b4.z;
        y.w = g4.w * (x.w - mean) * rstd + b4.w;
        reinterpret_cast<fx4*>(out)[(size_t)b * 32 + tid] = y;
    }
}

extern "C" void kernel_launch(void* const* d_in, const int* in_sizes, int n_in,
                              void* d_out, int out_size, void* d_ws, size_t ws_size,
                              hipStream_t stream) {
    const float* H      = (const float*)d_in[0];
    const int*   indice = (const int*)  d_in[1];
    const float* W      = (const float*)d_in[2];
    const float* bias   = (const float*)d_in[3];
    const float* gamma  = (const float*)d_in[4];
    const float* beta   = (const float*)d_in[5];
    float* out = (float*)d_out;
    fx4*   ws  = (fx4*)d_ws;   // needs B*CHUNKS*D floats = 1 MB

    colsum_kernel<<<dim3(B * CHUNKS), dim3(256), 0, stream>>>(H, ws);
    gather_dense_ln<<<dim3(B), dim3(256), 0, stream>>>(
        H, indice, (const float*)ws, W, bias, gamma, beta, out);
}